// Round 8
// baseline (157.119 us; speedup 1.0000x reference)
//
#include <hip/hip_runtime.h>

typedef unsigned short u16;
typedef unsigned int u32;
typedef __bf16 bf16x8 __attribute__((ext_vector_type(8)));
typedef __bf16 bf16x2 __attribute__((ext_vector_type(2)));
typedef float f32x4 __attribute__((ext_vector_type(4)));
typedef float f32x2 __attribute__((ext_vector_type(2)));
typedef u32 u32x4 __attribute__((ext_vector_type(4)));
typedef u32 u32x2 __attribute__((ext_vector_type(2)));
typedef short s16x4 __attribute__((ext_vector_type(4)));

#define DEVI __device__ __forceinline__

#if defined(__has_builtin)
#if __has_builtin(__builtin_amdgcn_exp2f)
#define EXP2F(x) __builtin_amdgcn_exp2f(x)
#endif
#endif
#ifndef EXP2F
#define EXP2F(x) exp2f(x)
#endif

#define MFMA16(a, b, c) __builtin_amdgcn_mfma_f32_16x16x32_bf16(a, b, c, 0, 0, 0)
#define MFMA1K(a, b, c) __builtin_amdgcn_mfma_f32_16x16x16bf16_1k(a, b, c, 0, 0, 0)

typedef __attribute__((address_space(1))) u32 gu32;
typedef __attribute__((address_space(3))) u32 lu32;
// async global->LDS, 16B per lane; LDS dest = wave-uniform base + lane*16
DEVI void gll16(const u16* g, u16* l) {
    __builtin_amdgcn_global_load_lds((const gu32*)g, (lu32*)l, 16, 0, 0);
}
#define WAIT_VM0() __builtin_amdgcn_s_waitcnt(0x0f70)  // vmcnt(0) only

DEVI u16 f2bf(float f) {
    u32 u = __builtin_bit_cast(u32, f);
    u = (u + 0x7FFFu + ((u >> 16) & 1u)) >> 16;
    return (u16)u;
}
DEVI float bf2f(u16 h) {
    u32 u = ((u32)h) << 16;
    return __builtin_bit_cast(float, u);
}
DEVI float bfhi(u32 u) { return __builtin_bit_cast(float, u & 0xFFFF0000u); }
DEVI float bflo(u32 u) { return __builtin_bit_cast(float, u << 16); }
DEVI bf16x8 bc8(u32x4 u) { return __builtin_bit_cast(bf16x8, u); }
DEVI u32 pack2(float a, float b) {
    f32x2 v = {a, b};
    bf16x2 h = __builtin_convertvector(v, bf16x2);
    return __builtin_bit_cast(u32, h);
}

// q scale: dh^-0.5 * log2(e)  (bakes natural-exp into exp2)
#define QSCALE 0.18033688011112042f

// ---------------------------------------------------------------------------
// K0: fused prep. Blocks [0,512): transpose+cast x -> xt[b][p][c] bf16.
//     Blocks [512,768): cast weights + rel tables (rel zero-padded to 128 rows).
__global__ __launch_bounds__(256) void k_prep(const float* __restrict__ x,
                                              const float* __restrict__ wq,
                                              const float* __restrict__ wo,
                                              const float* __restrict__ relh,
                                              const float* __restrict__ relw,
                                              u16* __restrict__ xt, u16* __restrict__ wqb,
                                              u16* __restrict__ wob, u16* __restrict__ relhb,
                                              u16* __restrict__ relwb) {
    int bid = blockIdx.x;
    int t = threadIdx.x;
    if (bid < 512) {
        int pm = bid & 63, cm = (bid >> 6) & 3, b = bid >> 8;
        int p0 = pm * 64, c0 = cm * 64;
        __shared__ float tile[64][65];
#pragma unroll
        for (int it = 0; it < 16; ++it) {
            int idx = it * 256 + t;
            int cl = idx >> 6, pl = idx & 63;
            tile[cl][pl] = x[((size_t)(b * 256 + c0 + cl)) * 4096 + p0 + pl];
        }
        __syncthreads();
#pragma unroll
        for (int it = 0; it < 16; ++it) {
            int idx = it * 256 + t;
            int pl = idx >> 6, cl = idx & 63;
            xt[((size_t)(b * 4096 + p0 + pl)) * 256 + c0 + cl] = f2bf(tile[cl][pl]);
        }
    } else {
        int i0 = (bid - 512) * 256 + t;  // 65536 stride
#pragma unroll
        for (int i = i0; i < 196608; i += 65536) wqb[i] = f2bf(wq[i]);
        if (i0 < 65536) wob[i0] = f2bf(wo[i0]);
        if (i0 < 8192) {
            relhb[i0] = (i0 < 8128) ? f2bf(relh[i0]) : (u16)0;
            relwb[i0] = (i0 < 8128) ? f2bf(relw[i0]) : (u16)0;
        }
    }
}

// ---------------------------------------------------------------------------
// K1: QKV projection GEMM + fused rel-bias tables.
// B-tile staged via global_load_lds into UNPADDED rows (512 B) with mod-32
// chunk swizzle: LDS pos p of row r holds global 16B-chunk (p+r)&31.
__global__ __launch_bounds__(256) void k_qkv(const u16* __restrict__ xt, const u16* __restrict__ wqb,
                                             const u16* __restrict__ relwb,
                                             const u16* __restrict__ relhb,
                                             u16* __restrict__ q, u16* __restrict__ k,
                                             u16* __restrict__ vt, u16* __restrict__ Wabs,
                                             u16* __restrict__ Habs) {
    int pm = blockIdx.x, on = blockIdx.y, b = blockIdx.z;
    int p0 = pm * 64, o0 = on * 64;
    __shared__ __align__(16) u16 Sm[64 * 256];  // 32 KB B-tile; later T[64*72]+Ls[128*72]
    int t = threadIdx.x;
    int wv = t >> 6, l = t & 63, quad = l >> 4, li = l & 15;

    u32x4 areg[8];
    const u32x4* arow = (const u32x4*)(xt + ((size_t)(b * 4096 + p0 + wv * 16 + li)) * 256);
#pragma unroll
    for (int kc = 0; kc < 8; ++kc) areg[kc] = arow[kc * 4 + quad];

    {
        int pc = l & 31;
#pragma unroll
        for (int i = 0; i < 8; ++i) {
            int r = wv * 16 + i * 2 + (l >> 5);
            gll16(wqb + (size_t)(o0 + r) * 256 + ((pc + r) & 31) * 8,
                  Sm + (wv * 16 + i * 2) * 256);
        }
    }
    WAIT_VM0();
    __syncthreads();

    f32x4 acc[4] = {{0, 0, 0, 0}, {0, 0, 0, 0}, {0, 0, 0, 0}, {0, 0, 0, 0}};
#pragma unroll
    for (int kc = 0; kc < 8; ++kc) {
        bf16x8 a = bc8(areg[kc]);
#pragma unroll
        for (int ct = 0; ct < 4; ++ct) {
            bf16x8 bb = bc8(*(const u32x4*)(Sm + (ct * 16 + li) * 256 +
                                            (((kc * 4 + quad) - (ct * 16 + li)) & 31) * 8));
            acc[ct] = MFMA16(a, bb, acc[ct]);
        }
    }

    int tensor = on >> 2, head = on & 3;
    if (tensor == 2) {
        __syncthreads();
        u16* T = Sm;  // [64 d][72 p]
#pragma unroll
        for (int ct = 0; ct < 4; ++ct)
#pragma unroll
            for (int r = 0; r < 4; ++r)
                T[(ct * 16 + li) * 72 + wv * 16 + quad * 4 + r] = f2bf(acc[ct][r]);
        __syncthreads();
        int dr = t >> 2, pc = (t & 3) * 16;
        u32x4* g = (u32x4*)(vt + ((size_t)((b * 4 + head) * 64 + dr)) * 4096 + p0 + pc);
        const u32x4* s2 = (const u32x4*)(T + dr * 72 + pc);
        g[0] = s2[0];
        g[1] = s2[1];
    } else {
        u16* outp = (tensor == 0) ? q : k;
        float sc = (tensor == 0) ? QSCALE : 1.0f;
#pragma unroll
        for (int ct = 0; ct < 4; ++ct)
#pragma unroll
            for (int r = 0; r < 4; ++r) {
                int p = p0 + wv * 16 + quad * 4 + r;
                int d = ct * 16 + li;
                outp[((size_t)((b * 4 + head) * 4096 + p)) * 64 + d] = f2bf(acc[ct][r] * sc);
            }
        if (tensor == 0) {
            // ---- fused rel-bias tables ----
            int bh = b * 4 + head;
            u16* T = Sm;             // [64 p][72 d]
            u16* Ls = Sm + 64 * 72;  // [128 r][72 d]
            __syncthreads();         // all GEMM Sm reads done
#pragma unroll
            for (int ct = 0; ct < 4; ++ct)
#pragma unroll
                for (int r = 0; r < 4; ++r)
                    T[(wv * 16 + quad * 4 + r) * 72 + ct * 16 + li] = f2bf(acc[ct][r] * QSCALE);
            {
                int row = t >> 1, half = t & 1;
                const u32x4* g2 = (const u32x4*)(relwb + row * 64 + half * 32);
                u32x4* s2 = (u32x4*)(Ls + row * 72 + half * 32);
#pragma unroll
                for (int kk = 0; kk < 4; ++kk) s2[kk] = g2[kk];
            }
            __syncthreads();
            u32x4 aq2[2];
            aq2[0] = *(const u32x4*)(T + (wv * 16 + li) * 72 + quad * 8);
            aq2[1] = *(const u32x4*)(T + (wv * 16 + li) * 72 + 32 + quad * 8);

            f32x4 acc2[8];
#pragma unroll
            for (int ct = 0; ct < 8; ++ct) acc2[ct] = (f32x4){0.f, 0.f, 0.f, 0.f};
#pragma unroll
            for (int kc = 0; kc < 2; ++kc) {
                bf16x8 a = bc8(aq2[kc]);
#pragma unroll
                for (int ct = 0; ct < 8; ++ct) {
                    bf16x8 bb = bc8(*(const u32x4*)(Ls + (ct * 16 + li) * 72 + kc * 32 + quad * 8));
                    acc2[ct] = MFMA16(a, bb, acc2[ct]);
                }
            }
#pragma unroll
            for (int ct = 0; ct < 8; ++ct)
#pragma unroll
                for (int r = 0; r < 4; ++r) {
                    int row = wv * 16 + quad * 4 + r;
                    int j = (ct * 16 + li) - 63 + row;  // shift = y = row
                    if (j >= 0 && j < 64)
                        Wabs[((size_t)(bh * 4096 + p0 + row)) * 64 + j] = f2bf(acc2[ct][r]);
                }
            __syncthreads();  // Ls reads done
            {
                int row = t >> 1, half = t & 1;
                const u32x4* g2 = (const u32x4*)(relhb + row * 64 + half * 32);
                u32x4* s2 = (u32x4*)(Ls + row * 72 + half * 32);
#pragma unroll
                for (int kk = 0; kk < 4; ++kk) s2[kk] = g2[kk];
            }
            __syncthreads();
#pragma unroll
            for (int ct = 0; ct < 8; ++ct) acc2[ct] = (f32x4){0.f, 0.f, 0.f, 0.f};
#pragma unroll
            for (int kc = 0; kc < 2; ++kc) {
                bf16x8 a = bc8(aq2[kc]);
#pragma unroll
                for (int ct = 0; ct < 8; ++ct) {
                    bf16x8 bb = bc8(*(const u32x4*)(Ls + (ct * 16 + li) * 72 + kc * 32 + quad * 8));
                    acc2[ct] = MFMA16(a, bb, acc2[ct]);
                }
            }
#pragma unroll
            for (int ct = 0; ct < 8; ++ct)
#pragma unroll
                for (int r = 0; r < 4; ++r) {
                    int row = wv * 16 + quad * 4 + r;
                    int j = (ct * 16 + li) - 63 + pm;  // shift = x = pm
                    if (j >= 0 && j < 64)
                        Habs[((size_t)(bh * 4096 + p0 + row)) * 64 + j] = f2bf(acc2[ct][r]);
                }
        }
    }
}

// ---------------------------------------------------------------------------
// K3: flash attention v7. K-split x2 (512 blocks, 32 iters).
//  - K/V staged by global_load_lds (16B/lane) into UNPADDED 128B rows,
//    mod-8 chunk swizzle (LDS pos p of row r holds global chunk (p+r)&7)
//  - biases folded into MFMA C-init; P register-resident (S^T C == PV A identity)
//  - double-buffer, one s_waitcnt vmcnt(0) + one barrier per iter
__global__ __launch_bounds__(256, 2) void k_flash(const u16* __restrict__ q,
                                                  const u16* __restrict__ kg,
                                                  const u16* __restrict__ vt,
                                                  const u16* __restrict__ Wabs,
                                                  const u16* __restrict__ Habs,
                                                  u16* __restrict__ OP,
                                                  float* __restrict__ LS) {
    int pm = blockIdx.x, bh = blockIdx.y, ks = blockIdx.z;
    int p0 = pm * 128;
    __shared__ __align__(16) u16 Kt[2][64 * 64];
    __shared__ __align__(16) u16 Vl[2][64 * 64];
    __shared__ __align__(16) u16 Hl[128 * 40];
    int t = threadIdx.x, wv = t >> 6, l = t & 63, quad = l >> 4, li = l & 15;
    int rbase = wv * 32;

    // Q B-frags for both row-sets
    u32x4 aq[2][2];
#pragma unroll
    for (int rs = 0; rs < 2; ++rs) {
        const u32x4* qrow =
            (const u32x4*)(q + ((size_t)(bh * 4096 + p0 + rbase + rs * 16 + li)) * 64);
        aq[rs][0] = qrow[quad];
        aq[rs][1] = qrow[4 + quad];
    }

    // width-bias as f32x4 per (rs,ct), aligned to the S^T C-frag
    f32x4 wb4[2][4];
#pragma unroll
    for (int rs = 0; rs < 2; ++rs)
#pragma unroll
        for (int ct = 0; ct < 4; ++ct) {
            const u32* wp = (const u32*)(Wabs +
                                         ((size_t)(bh * 4096 + p0 + rbase + rs * 16 + li)) * 64 +
                                         ct * 16 + quad * 4);
            u32 lo = wp[0], hi = wp[1];
            wb4[rs][ct] = (f32x4){bflo(lo), bfhi(lo), bflo(hi), bfhi(hi)};
        }

    // height-bias tile: 128 rows x 32 local kt cols, bf16 (stride 40 -> 16B-aligned)
    {
        int row = t >> 1, half = t & 1;
        const u32x4* g =
            (const u32x4*)(Habs + ((size_t)(bh * 4096 + p0 + row)) * 64 + ks * 32 + half * 16);
        *(u32x4*)(Hl + row * 40 + half * 16) = g[0];
        *(u32x4*)(Hl + row * 40 + half * 16 + 8) = g[1];
    }

    // gll staging constants: per wave 2 instr x (8 rows x 8 chunks of 16B)
    int grow = wv * 16 + (l >> 3);  // +8 for i=1
    int gchk = l & 7;

    // issue tile 0 into buffer 0
    {
        int j0 = ks * 2048;
#pragma unroll
        for (int i = 0; i < 2; ++i) {
            int r = grow + i * 8;
            gll16(kg + ((size_t)(bh * 4096 + j0 + r)) * 64 + ((gchk + r) & 7) * 8,
                  (u16*)Kt[0] + (wv * 16 + i * 8) * 64);
            gll16(vt + ((size_t)(bh * 64 + r)) * 4096 + j0 + ((gchk + r) & 7) * 8,
                  (u16*)Vl[0] + (wv * 16 + i * 8) * 64);
        }
    }

    f32x4 oacc[2][5];
#pragma unroll
    for (int rs = 0; rs < 2; ++rs)
#pragma unroll
        for (int ct = 0; ct < 5; ++ct) oacc[rs][ct] = (f32x4){0.f, 0.f, 0.f, 0.f};

    const s16x4 ones = {(short)0x3F80, (short)0x3F80, (short)0x3F80, (short)0x3F80};

    for (int kt = 0; kt < 32; ++kt) {
        WAIT_VM0();       // my wave's glls for buf[cur] have landed
        __syncthreads();  // everyone's landed; prior reads of buf[nxt] done
        int cur = kt & 1;
        const u16* Kc = (const u16*)Kt[cur];
        const u16* Vc = (const u16*)Vl[cur];
        if (kt < 31) {
            int j0 = (ks * 32 + kt + 1) * 64;
#pragma unroll
            for (int i = 0; i < 2; ++i) {
                int r = grow + i * 8;
                gll16(kg + ((size_t)(bh * 4096 + j0 + r)) * 64 + ((gchk + r) & 7) * 8,
                      (u16*)Kt[cur ^ 1] + (wv * 16 + i * 8) * 64);
                gll16(vt + ((size_t)(bh * 64 + r)) * 4096 + j0 + ((gchk + r) & 7) * 8,
                      (u16*)Vl[cur ^ 1] + (wv * 16 + i * 8) * 64);
            }
        }

        // S^T = K · Q^T with bias-initialized accumulators (swizzled K reads)
        float hh0 = bf2f(Hl[(rbase + li) * 40 + kt]);
        float hh1 = bf2f(Hl[(rbase + 16 + li) * 40 + kt]);
        f32x4 s[2][4];
#pragma unroll
        for (int ct = 0; ct < 4; ++ct) {
            s[0][ct] = wb4[0][ct] + hh0;
            s[1][ct] = wb4[1][ct] + hh1;
        }
#pragma unroll
        for (int kc = 0; kc < 2; ++kc) {
            bf16x8 b0 = bc8(aq[0][kc]), b1 = bc8(aq[1][kc]);
#pragma unroll
            for (int ct = 0; ct < 4; ++ct) {
                bf16x8 af = bc8(*(const u32x4*)(Kc + (ct * 16 + li) * 64 +
                                                (((kc * 4 + quad) - li) & 7) * 8));
                s[0][ct] = MFMA16(af, b0, s[0][ct]);
                s[1][ct] = MFMA16(af, b1, s[1][ct]);
            }
        }

        // exp2 + packed bf16 P-fragments (registers only)
        s16x4 pf[2][4];
#pragma unroll
        for (int rs = 0; rs < 2; ++rs)
#pragma unroll
            for (int ct = 0; ct < 4; ++ct) {
                u32x2 pp;
                pp.x = pack2(EXP2F(s[rs][ct][0]), EXP2F(s[rs][ct][1]));
                pp.y = pack2(EXP2F(s[rs][ct][2]), EXP2F(s[rs][ct][3]));
                pf[rs][ct] = __builtin_bit_cast(s16x4, pp);
            }

        // O += P · V (swizzled V reads); dt=4 accumulates row sums via ones
#pragma unroll
        for (int jt = 0; jt < 4; ++jt) {
            s16x4 a0 = pf[0][jt], a1 = pf[1][jt];
#pragma unroll
            for (int dt = 0; dt < 4; ++dt) {
                s16x4 bv = __builtin_bit_cast(
                    s16x4, *(const u32x2*)(Vc + (dt * 16 + li) * 64 +
                                           (((2 * jt + (quad >> 1)) - li) & 7) * 8 +
                                           (quad & 1) * 4));
                oacc[0][dt] = MFMA1K(a0, bv, oacc[0][dt]);
                oacc[1][dt] = MFMA1K(a1, bv, oacc[1][dt]);
            }
            oacc[0][4] = MFMA1K(a0, ones, oacc[0][4]);
            oacc[1][4] = MFMA1K(a1, ones, oacc[1][4]);
        }
    }

    // store bf16 partials + fp32 row-sums (normalization in k_out2)
#pragma unroll
    for (int rs = 0; rs < 2; ++rs) {
#pragma unroll
        for (int ct = 0; ct < 4; ++ct)
#pragma unroll
            for (int r = 0; r < 4; ++r) {
                int p = p0 + rbase + rs * 16 + quad * 4 + r;
                OP[((size_t)((ks * 8 + bh) * 4096 + p)) * 64 + ct * 16 + li] =
                    f2bf(oacc[rs][ct][r]);
            }
        if (li == 0) {
#pragma unroll
            for (int r = 0; r < 4; ++r) {
                int p = p0 + rbase + rs * 16 + quad * 4 + r;
                LS[(size_t)(ks * 8 + bh) * 4096 + p] = oacc[rs][4][r];
            }
        }
    }
}

// ---------------------------------------------------------------------------
// K4: fused combine (2 K-slices) + out-projection + residual. grid (64 pm, 2 b, 2 coh).
__global__ __launch_bounds__(256) void k_out2(const u16* __restrict__ wob,
                                              const u16* __restrict__ OP,
                                              const float* __restrict__ LS,
                                              const float* __restrict__ x,
                                              float* __restrict__ out) {
    int pm = blockIdx.x, b = blockIdx.y, coh = blockIdx.z;
    int p0 = pm * 64;
    __shared__ __align__(16) u16 Bt[64 * 264];
    int t = threadIdx.x, wv = t >> 6, l = t & 63, quad = l >> 4, li = l & 15;

    {
        int row = t >> 2, head = t & 3;
        int bh = b * 4 + head;
        int p = p0 + row;
        const u32x4* o0p = (const u32x4*)(OP + ((size_t)(bh * 4096 + p)) * 64);
        const u32x4* o1p = (const u32x4*)(OP + ((size_t)((8 + bh) * 4096 + p)) * 64);
        float linv = 1.0f / (LS[(size_t)bh * 4096 + p] + LS[(size_t)(8 + bh) * 4096 + p]);
        u16* dst = Bt + row * 264 + head * 64;
#pragma unroll
        for (int kk = 0; kk < 8; ++kk) {
            u32x4 a = o0p[kk], c = o1p[kk];
            u32x4 pk;
            pk.x = pack2((bflo(a.x) + bflo(c.x)) * linv, (bfhi(a.x) + bfhi(c.x)) * linv);
            pk.y = pack2((bflo(a.y) + bflo(c.y)) * linv, (bfhi(a.y) + bfhi(c.y)) * linv);
            pk.z = pack2((bflo(a.z) + bflo(c.z)) * linv, (bfhi(a.z) + bfhi(c.z)) * linv);
            pk.w = pack2((bflo(a.w) + bflo(c.w)) * linv, (bfhi(a.w) + bfhi(c.w)) * linv);
            *(u32x4*)(dst + kk * 8) = pk;
        }
    }
    __syncthreads();

#pragma unroll
    for (int ci = 0; ci < 2; ++ci) {
        int com = coh * 2 + ci;
        int co0 = com * 64;
        f32x4 acc[4] = {{0, 0, 0, 0}, {0, 0, 0, 0}, {0, 0, 0, 0}, {0, 0, 0, 0}};
        const u32x4* arow = (const u32x4*)(wob + (size_t)(co0 + wv * 16 + li) * 256);
#pragma unroll
        for (int kc = 0; kc < 8; ++kc) {
            bf16x8 a = bc8(arow[kc * 4 + quad]);
#pragma unroll
            for (int ct = 0; ct < 4; ++ct) {
                bf16x8 bb = bc8(*(const u32x4*)(Bt + (ct * 16 + li) * 264 + kc * 32 + quad * 8));
                acc[ct] = MFMA16(a, bb, acc[ct]);
            }
        }
#pragma unroll
        for (int ct = 0; ct < 4; ++ct)
#pragma unroll
            for (int r = 0; r < 4; ++r) {
                size_t idx =
                    ((size_t)(b * 256 + co0 + wv * 16 + quad * 4 + r)) * 4096 + p0 + ct * 16 + li;
                out[idx] = acc[ct][r] + x[idx];
            }
    }
}

// ---------------------------------------------------------------------------
extern "C" void kernel_launch(void* const* d_in, const int* in_sizes, int n_in, void* d_out,
                              int out_size, void* d_ws, size_t ws_size, hipStream_t stream) {
    const float* x = (const float*)d_in[0];
    const float* wqkv = (const float*)d_in[1];
    const float* wout = (const float*)d_in[2];
    const float* relh = (const float*)d_in[3];
    const float* relw = (const float*)d_in[4];
    float* out = (float*)d_out;
    char* ws = (char*)d_ws;

    u16* xt = (u16*)(ws + 0);               // 4,194,304 (dead after k_qkv)
    u16* wqb = (u16*)(ws + 4194304);        //   393,216
    u16* wob = (u16*)(ws + 4587520);        //   131,072
    u16* relwb = (u16*)(ws + 4718592);      //    16,384
    u16* relhb = (u16*)(ws + 4734976);      //    16,384
    u16* qb = (u16*)(ws + 4751360);         // 4,194,304
    u16* kb = (u16*)(ws + 8945664);         // 4,194,304
    u16* vtb = (u16*)(ws + 13139968);       // 4,194,304
    u16* Wabs = (u16*)(ws + 17334272);      // 4,194,304
    u16* Habs = (u16*)(ws + 21528576);      // 4,194,304
    u16* OPart = (u16*)(ws + 25722880);     // 8,388,608 (2 x 8 x 4096 x 64 bf16)
    float* LSum = (float*)(ws + 0);         //   262,144 (aliases dead xt)

    k_prep<<<768, 256, 0, stream>>>(x, wqkv, wout, relh, relw, xt, wqb, wob, relhb, relwb);
    k_qkv<<<dim3(64, 12, 2), 256, 0, stream>>>(xt, wqb, relwb, relhb, qb, kb, vtb, Wabs, Habs);
    k_flash<<<dim3(32, 8, 2), 256, 0, stream>>>(qb, kb, vtb, Wabs, Habs, OPart, LSum);
    k_out2<<<dim3(64, 2, 2), 256, 0, stream>>>(wob, OPart, LSum, x, out);
}